// Round 3
// baseline (805.738 us; speedup 1.0000x reference)
//
#include <hip/hip_runtime.h>

#define BB    8
#define NN    20000
#define DD    640
#define RR    2500
#define NBINS 10
#define HID   128
#define MTOT  (BB*NN)        // 160000
#define SBLK  1024           // stats grid
#define OSTR  20             // per-feature LDS stride in out_kernel (80 B, 16-aligned)

// ---------------------------------------------------------------------------
// Kernel 1 (dominant, HBM-bound): pooled[b,r,bin].
// Segment bounds found in-block (threads 0/1 binary-search sorted res_id).
// A residue's x-data is one contiguous chunk of cnt*640 floats; stream with
// float4. Grid stride = 640 float4 = 2560 floats (multiple of D), so each
// thread's channel group (hence bin) is fixed. 16-lane shfl reduce, then
// 40 LDS atomics into 10 bins.
// ---------------------------------------------------------------------------
__global__ __launch_bounds__(640) void pool_kernel(const float* __restrict__ x,
                                                   const int* __restrict__ res_id,
                                                   float* __restrict__ pooled) {
    __shared__ float sbin[NBINS];
    __shared__ int sbounds[2];
    int br = blockIdx.x;
    int b = br / RR;
    int r = br - b * RR;
    int t = threadIdx.x;
    if (t < NBINS) sbin[t] = 0.f;
    if (t < 2) {                       // lower_bound(r) and lower_bound(r+1)
        int target = r + t;
        int lo = 0, hi = NN;
        while (lo < hi) {
            int mid = (lo + hi) >> 1;
            if (res_id[mid] < target) lo = mid + 1; else hi = mid;
        }
        sbounds[t] = lo;
    }
    __syncthreads();

    int s0  = sbounds[0];
    int cnt = sbounds[1] - s0;
    int nf4 = (cnt * DD) >> 2;
    const float4* xp = (const float4*)(x + (size_t)(b * NN + s0) * DD);

    float sum = 0.f;
    for (int idx = t; idx < nf4; idx += 640) {
        float4 v = xp[idx];
        sum += (v.x + v.y) + (v.z + v.w);
    }

    sum += __shfl_down(sum, 8, 16);
    sum += __shfl_down(sum, 4, 16);
    sum += __shfl_down(sum, 2, 16);
    sum += __shfl_down(sum, 1, 16);
    if ((t & 15) == 0) {
        int bin = ((t << 2) % DD) >> 6;
        atomicAdd(&sbin[bin], sum);
    }
    __syncthreads();
    if (t < NBINS) {
        float inv = cnt > 0 ? 1.f / (64.f * (float)cnt) : 0.f;
        pooled[(size_t)(b * RR + r) * NBINS + t] = sbin[t] * inv;
    }
}

// ---------------------------------------------------------------------------
// Kernel 2: BN statistics of h = relu(feat @ W1 + b1), per feature k.
// Block = 128 threads (thread = feature k); grid-stride over atoms; per-block
// partials -> ws (no atomics).
// ---------------------------------------------------------------------------
__global__ __launch_bounds__(128) void stats_kernel(const float* __restrict__ pooled,
                                                    const float* __restrict__ cond,
                                                    const int* __restrict__ res_id,
                                                    const float* __restrict__ W1,
                                                    const float* __restrict__ b1,
                                                    float* __restrict__ partial) {
    int k = threadIdx.x;
    float w[13];
    #pragma unroll
    for (int j = 0; j < 13; j++) w[j] = W1[j * HID + k];
    float bk = b1[k];

    float s = 0.f, s2 = 0.f;
    for (int i = blockIdx.x; i < MTOT; i += SBLK) {
        int b = i / NN;
        int n = i - b * NN;
        int rid = res_id[n];
        const float* pr = pooled + (size_t)(b * RR + rid) * NBINS;
        const float* cr = cond + (size_t)n * 3;
        float h = bk;
        #pragma unroll
        for (int j = 0; j < NBINS; j++) h = fmaf(pr[j], w[j], h);
        h = fmaf(cr[0], w[10], h);
        h = fmaf(cr[1], w[11], h);
        h = fmaf(cr[2], w[12], h);
        h = fmaxf(h, 0.f);
        s += h;
        s2 = fmaf(h, h, s2);
    }
    partial[blockIdx.x * 256 + k]       = s;
    partial[blockIdx.x * 256 + 128 + k] = s2;
}

// ---------------------------------------------------------------------------
// Kernel 3: reduce partials, fold BN into W2eff/b2eff.
// ---------------------------------------------------------------------------
__global__ __launch_bounds__(1024) void finalize_kernel(const float* __restrict__ partial,
                                                        const float* __restrict__ gamma,
                                                        const float* __restrict__ beta,
                                                        const float* __restrict__ W2,
                                                        const float* __restrict__ b2,
                                                        float* __restrict__ W2eff,
                                                        float* __restrict__ b2eff) {
    int t = threadIdx.x;            // 0..1023
    int slot = t & 255;
    int grp  = t >> 8;              // 0..3
    float acc = 0.f;
    for (int bi = grp; bi < SBLK; bi += 4) acc += partial[bi * 256 + slot];

    __shared__ float part4[4][256];
    __shared__ float contrib[HID * 3];
    part4[grp][slot] = acc;
    __syncthreads();

    if (t < HID) {
        float s  = part4[0][t] + part4[1][t] + part4[2][t] + part4[3][t];
        float s2 = part4[0][128 + t] + part4[1][128 + t] + part4[2][128 + t] + part4[3][128 + t];
        const float invM = 1.f / (float)MTOT;
        float mu  = s * invM;
        float var = fmaxf(s2 * invM - mu * mu, 0.f);
        float rs  = rsqrtf(var + 1e-5f);
        float sc  = gamma[t] * rs;
        float tk  = beta[t] - mu * sc;
        #pragma unroll
        for (int j = 0; j < 3; j++) {
            float wv = W2[t * 3 + j];
            W2eff[t * 3 + j]   = sc * wv;
            contrib[t * 3 + j] = tk * wv;
        }
    }
    __syncthreads();
    if (t < 3) {
        float a2 = b2[t];
        for (int kk = 0; kk < HID; kk++) a2 += contrib[kk * 3 + t];
        b2eff[t] = a2;
    }
}

// ---------------------------------------------------------------------------
// Kernel 4: out[i][:] = W2eff^T relu(W1^T feat_i + b1) + b2eff.
// THREAD-PER-ATOM, no cross-lane shuffles. Weights packed in LDS with a
// 20-float stride per feature k: [0..12]=W1[:,k], [13..15]=W2eff[k][:],
// [16]=b1[k], [17..19]=pad. k*80 B is 16-aligned -> ds_read_b128 x4.
// Inner loop has uniform k => all lanes read the SAME LDS address
// (broadcast, conflict-free). 625 blocks x 256 threads == 160000 atoms.
// ---------------------------------------------------------------------------
__global__ __launch_bounds__(256) void out_kernel(const float* __restrict__ pooled,
                                                  const float* __restrict__ cond,
                                                  const int* __restrict__ res_id,
                                                  const float* __restrict__ W1,
                                                  const float* __restrict__ b1,
                                                  const float* __restrict__ W2eff,
                                                  const float* __restrict__ b2eff,
                                                  float* __restrict__ out) {
    __shared__ float sw[HID * OSTR];
    __shared__ float sb2[3];
    int t = threadIdx.x;
    for (int k = t; k < HID; k += 256) {
        #pragma unroll
        for (int j = 0; j < 13; j++) sw[k * OSTR + j] = W1[j * HID + k];
        sw[k * OSTR + 13] = W2eff[k * 3 + 0];
        sw[k * OSTR + 14] = W2eff[k * 3 + 1];
        sw[k * OSTR + 15] = W2eff[k * 3 + 2];
        sw[k * OSTR + 16] = b1[k];
    }
    if (t < 3) sb2[t] = b2eff[t];
    __syncthreads();

    int i = blockIdx.x * 256 + t;        // atom index (grid covers exactly MTOT)
    int b = i / NN;
    int n = i - b * NN;
    int rid = res_id[n];
    const float* pr = pooled + (size_t)(b * RR + rid) * NBINS;
    const float* cr = cond + (size_t)n * 3;

    float f[13];
    #pragma unroll
    for (int j = 0; j < NBINS; j++) f[j] = pr[j];
    f[10] = cr[0]; f[11] = cr[1]; f[12] = cr[2];

    float o0 = sb2[0], o1 = sb2[1], o2 = sb2[2];
    #pragma unroll 4
    for (int k = 0; k < HID; k++) {
        const float* wk = &sw[k * OSTR];
        float h = wk[16];
        #pragma unroll
        for (int j = 0; j < 13; j++) h = fmaf(f[j], wk[j], h);
        h = fmaxf(h, 0.f);
        o0 = fmaf(h, wk[13], o0);
        o1 = fmaf(h, wk[14], o1);
        o2 = fmaf(h, wk[15], o2);
    }
    out[(size_t)i * 3 + 0] = o0;
    out[(size_t)i * 3 + 1] = o1;
    out[(size_t)i * 3 + 2] = o2;
}

// ---------------------------------------------------------------------------
// Workspace layout (all fully rewritten every launch; no zero-init needed):
//   [16384, 816384)       pooled     (B*R*NBINS floats)
//   [1 MiB, 2 MiB)        partial    (SBLK*256 floats = 1 MiB)
//   [3 MiB, +1536)        W2eff
//   [3 MiB + 4096, +12)   b2eff
// ---------------------------------------------------------------------------
extern "C" void kernel_launch(void* const* d_in, const int* in_sizes, int n_in,
                              void* d_out, int out_size, void* d_ws, size_t ws_size,
                              hipStream_t stream) {
    const float* x      = (const float*)d_in[0];
    const float* cond   = (const float*)d_in[1];
    const int*   res_id = (const int*)  d_in[2];
    const float* W1     = (const float*)d_in[3];
    const float* b1     = (const float*)d_in[4];
    const float* gamma  = (const float*)d_in[5];
    const float* beta   = (const float*)d_in[6];
    const float* W2     = (const float*)d_in[7];
    const float* b2     = (const float*)d_in[8];
    float* out = (float*)d_out;

    char* w = (char*)d_ws;
    float* pooled    = (float*)(w + 16384);
    float* partial   = (float*)(w + (1 << 20));
    float* W2eff     = (float*)(w + (3 << 20));
    float* b2eff     = (float*)(w + (3 << 20) + 4096);

    hipLaunchKernelGGL(pool_kernel, dim3(BB * RR), dim3(640), 0, stream,
                       x, res_id, pooled);
    hipLaunchKernelGGL(stats_kernel, dim3(SBLK), dim3(128), 0, stream,
                       pooled, cond, res_id, W1, b1, partial);
    hipLaunchKernelGGL(finalize_kernel, dim3(1), dim3(1024), 0, stream,
                       partial, gamma, beta, W2, b2, W2eff, b2eff);
    hipLaunchKernelGGL(out_kernel, dim3(MTOT / 256), dim3(256), 0, stream,
                       pooled, cond, res_id, W1, b1, W2eff, b2eff, out);
}

// Round 4
// 722.657 us; speedup vs baseline: 1.1150x; 1.1150x over previous
//
#include <hip/hip_runtime.h>

#define BB    8
#define NN    20000
#define DD    640
#define RR    2500
#define NBINS 10
#define HID   128
#define MTOT  (BB*NN)        // 160000
#define SBLK  512            // stats grid (each block = 2 atom-groups of 128 threads)

// ---------------------------------------------------------------------------
// Kernel 0: segment bounds via binary search on sorted res_id; also zeroes
// the stats completion counter (ws is poisoned 0xAA before every launch).
// ---------------------------------------------------------------------------
__global__ void seg_bounds_kernel(const int* __restrict__ res_id,
                                  int* __restrict__ seg_start,
                                  int* __restrict__ counter) {
    int r = blockIdx.x * blockDim.x + threadIdx.x;
    if (r == 0) *counter = 0;
    if (r > RR) return;
    if (r == RR) { seg_start[RR] = NN; return; }
    int lo = 0, hi = NN;
    while (lo < hi) {
        int mid = (lo + hi) >> 1;
        if (res_id[mid] < r) lo = mid + 1; else hi = mid;
    }
    seg_start[r] = lo;
}

// ---------------------------------------------------------------------------
// Kernel 1 (dominant, HBM-bound): pooled[b,r,bin]. Round-2 version (measured
// at the HBM floor). Contiguous float4 streaming; grid stride 2560 floats is
// a multiple of D so each thread's bin is fixed; 16-lane shfl reduce + LDS
// atomics into 10 bins.
// ---------------------------------------------------------------------------
__global__ __launch_bounds__(640) void pool_kernel(const float* __restrict__ x,
                                                   const int* __restrict__ seg_start,
                                                   float* __restrict__ pooled) {
    __shared__ float sbin[NBINS];
    int br = blockIdx.x;
    int b = br / RR;
    int r = br - b * RR;
    int t = threadIdx.x;
    if (t < NBINS) sbin[t] = 0.f;
    __syncthreads();

    int s0  = seg_start[r];
    int cnt = seg_start[r + 1] - s0;
    int nf4 = (cnt * DD) >> 2;
    const float4* xp = (const float4*)(x + (size_t)(b * NN + s0) * DD);

    float sum = 0.f;
    for (int idx = t; idx < nf4; idx += 640) {
        float4 v = xp[idx];
        sum += (v.x + v.y) + (v.z + v.w);
    }

    sum += __shfl_down(sum, 8, 16);
    sum += __shfl_down(sum, 4, 16);
    sum += __shfl_down(sum, 2, 16);
    sum += __shfl_down(sum, 1, 16);
    if ((t & 15) == 0) {
        int bin = ((t << 2) % DD) >> 6;
        atomicAdd(&sbin[bin], sum);
    }
    __syncthreads();
    if (t < NBINS) {
        float inv = cnt > 0 ? 1.f / (64.f * (float)cnt) : 0.f;
        pooled[(size_t)(b * RR + r) * NBINS + t] = sbin[t] * inv;
    }
}

// ---------------------------------------------------------------------------
// Kernel 2: BN statistics of h = relu(feat @ W1 + b1) + FOLD (merged
// finalize). 512 blocks x 256 threads; thread = (k = t&127, g = t>>7).
// Per-block LDS merge of the two groups -> one 256-float partial row.
// Last block to finish (device-scope atomic counter) reduces all 512 rows
// and folds BN into W2eff/b2eff.
// ---------------------------------------------------------------------------
__global__ __launch_bounds__(256) void stats_fin_kernel(const float* __restrict__ pooled,
                                                        const float* __restrict__ cond,
                                                        const int* __restrict__ res_id,
                                                        const float* __restrict__ W1,
                                                        const float* __restrict__ b1,
                                                        const float* __restrict__ gamma,
                                                        const float* __restrict__ beta,
                                                        const float* __restrict__ W2,
                                                        const float* __restrict__ b2,
                                                        float* __restrict__ partial,
                                                        int* __restrict__ counter,
                                                        float* __restrict__ W2eff,
                                                        float* __restrict__ b2eff) {
    int t = threadIdx.x;
    int k = t & 127;
    int g = t >> 7;                       // 0..1
    float w[13];
    #pragma unroll
    for (int j = 0; j < 13; j++) w[j] = W1[j * HID + k];
    float bk = b1[k];

    float s = 0.f, s2 = 0.f;
    for (int i = blockIdx.x * 2 + g; i < MTOT; i += 2 * SBLK) {
        int b = i / NN;
        int n = i - b * NN;
        int rid = res_id[n];
        const float* pr = pooled + (size_t)(b * RR + rid) * NBINS;
        const float* cr = cond + (size_t)n * 3;
        float h = bk;
        #pragma unroll
        for (int j = 0; j < NBINS; j++) h = fmaf(pr[j], w[j], h);
        h = fmaf(cr[0], w[10], h);
        h = fmaf(cr[1], w[11], h);
        h = fmaf(cr[2], w[12], h);
        h = fmaxf(h, 0.f);
        s += h;
        s2 = fmaf(h, h, s2);
    }

    __shared__ float red[2][256];
    red[g][k]       = s;
    red[g][128 + k] = s2;
    __syncthreads();
    // one 256-float partial row per block
    partial[blockIdx.x * 256 + t] = red[0][t] + red[1][t];

    // completion counter (device scope); last block performs the fold
    __threadfence();
    __shared__ int is_last;
    if (t == 0) is_last = (atomicAdd(counter, 1) == SBLK - 1);
    __syncthreads();
    if (!is_last) return;
    __threadfence();                      // acquire: make all partials visible

    float acc = 0.f;
    for (int bi = 0; bi < SBLK; bi++) acc += partial[bi * 256 + t];
    __shared__ float tot[256];
    __shared__ float contrib[HID * 3];
    tot[t] = acc;
    __syncthreads();

    if (t < HID) {
        const float invM = 1.f / (float)MTOT;
        float mu  = tot[t] * invM;
        float var = fmaxf(tot[128 + t] * invM - mu * mu, 0.f);
        float rs  = rsqrtf(var + 1e-5f);
        float sc  = gamma[t] * rs;
        float tk  = beta[t] - mu * sc;
        #pragma unroll
        for (int j = 0; j < 3; j++) {
            float wv = W2[t * 3 + j];
            W2eff[t * 3 + j]   = sc * wv;
            contrib[t * 3 + j] = tk * wv;
        }
    }
    __syncthreads();
    if (t < 3) {
        float a2 = b2[t];
        for (int kk = 0; kk < HID; kk++) a2 += contrib[kk * 3 + t];
        b2eff[t] = a2;
    }
}

// ---------------------------------------------------------------------------
// Kernel 3: out[i][:] = W2eff^T relu(W1^T feat_i + b1) + b2eff.
// Round-2 version: wave per atom iteration, lane l owns features l and l+64,
// 64-lane butterfly, lane 0 writes 3 floats.
// ---------------------------------------------------------------------------
__global__ __launch_bounds__(256) void out_kernel(const float* __restrict__ pooled,
                                                  const float* __restrict__ cond,
                                                  const int* __restrict__ res_id,
                                                  const float* __restrict__ W1,
                                                  const float* __restrict__ b1,
                                                  const float* __restrict__ W2eff,
                                                  const float* __restrict__ b2eff,
                                                  float* __restrict__ out) {
    int lane = threadIdx.x & 63;
    int wid  = (blockIdx.x * blockDim.x + threadIdx.x) >> 6;
    int nw   = (gridDim.x * blockDim.x) >> 6;
    int k1 = lane, k2 = lane + 64;

    float wa[13], wb[13];
    #pragma unroll
    for (int j = 0; j < 13; j++) {
        wa[j] = W1[j * HID + k1];
        wb[j] = W1[j * HID + k2];
    }
    float b1a = b1[k1], b1b = b1[k2];
    float wa0 = W2eff[k1 * 3 + 0], wa1 = W2eff[k1 * 3 + 1], wa2 = W2eff[k1 * 3 + 2];
    float wb0 = W2eff[k2 * 3 + 0], wb1 = W2eff[k2 * 3 + 1], wb2 = W2eff[k2 * 3 + 2];
    float e0 = b2eff[0], e1 = b2eff[1], e2 = b2eff[2];

    for (int i = wid; i < MTOT; i += nw) {
        int b = i / NN;
        int n = i - b * NN;
        int rid = res_id[n];
        const float* pr = pooled + (size_t)(b * RR + rid) * NBINS;
        const float* cr = cond + (size_t)n * 3;

        float h1 = b1a, h2 = b1b;
        #pragma unroll
        for (int j = 0; j < NBINS; j++) {
            h1 = fmaf(pr[j], wa[j], h1);
            h2 = fmaf(pr[j], wb[j], h2);
        }
        h1 = fmaf(cr[0], wa[10], h1); h1 = fmaf(cr[1], wa[11], h1); h1 = fmaf(cr[2], wa[12], h1);
        h2 = fmaf(cr[0], wb[10], h2); h2 = fmaf(cr[1], wb[11], h2); h2 = fmaf(cr[2], wb[12], h2);
        h1 = fmaxf(h1, 0.f);
        h2 = fmaxf(h2, 0.f);

        float p0 = h1 * wa0 + h2 * wb0;
        float p1 = h1 * wa1 + h2 * wb1;
        float p2 = h1 * wa2 + h2 * wb2;
        #pragma unroll
        for (int m = 1; m < 64; m <<= 1) {
            p0 += __shfl_xor(p0, m, 64);
            p1 += __shfl_xor(p1, m, 64);
            p2 += __shfl_xor(p2, m, 64);
        }
        if (lane == 0) {
            out[(size_t)i * 3 + 0] = p0 + e0;
            out[(size_t)i * 3 + 1] = p1 + e1;
            out[(size_t)i * 3 + 2] = p2 + e2;
        }
    }
}

// ---------------------------------------------------------------------------
// Workspace layout:
//   [0, 10004)            seg_start  (R+1 ints)
//   [12288, +4)           counter    (int, zeroed by seg_bounds)
//   [16384, 816384)       pooled     (B*R*NBINS floats)
//   [1 MiB, 1.5 MiB)      partial    (SBLK*256 floats)
//   [3 MiB, +1536)        W2eff
//   [3 MiB + 4096, +12)   b2eff
// ---------------------------------------------------------------------------
extern "C" void kernel_launch(void* const* d_in, const int* in_sizes, int n_in,
                              void* d_out, int out_size, void* d_ws, size_t ws_size,
                              hipStream_t stream) {
    const float* x      = (const float*)d_in[0];
    const float* cond   = (const float*)d_in[1];
    const int*   res_id = (const int*)  d_in[2];
    const float* W1     = (const float*)d_in[3];
    const float* b1     = (const float*)d_in[4];
    const float* gamma  = (const float*)d_in[5];
    const float* beta   = (const float*)d_in[6];
    const float* W2     = (const float*)d_in[7];
    const float* b2     = (const float*)d_in[8];
    float* out = (float*)d_out;

    char* w = (char*)d_ws;
    int*   seg_start = (int*)  (w);
    int*   counter   = (int*)  (w + 12288);
    float* pooled    = (float*)(w + 16384);
    float* partial   = (float*)(w + (1 << 20));
    float* W2eff     = (float*)(w + (3 << 20));
    float* b2eff     = (float*)(w + (3 << 20) + 4096);

    hipLaunchKernelGGL(seg_bounds_kernel, dim3(10), dim3(256), 0, stream,
                       res_id, seg_start, counter);
    hipLaunchKernelGGL(pool_kernel, dim3(BB * RR), dim3(640), 0, stream,
                       x, seg_start, pooled);
    hipLaunchKernelGGL(stats_fin_kernel, dim3(SBLK), dim3(256), 0, stream,
                       pooled, cond, res_id, W1, b1, gamma, beta, W2, b2,
                       partial, counter, W2eff, b2eff);
    hipLaunchKernelGGL(out_kernel, dim3(1024), dim3(256), 0, stream,
                       pooled, cond, res_id, W1, b1, W2eff, b2eff, out);
}